// Round 6
// baseline (103.839 us; speedup 1.0000x reference)
//
#include <hip/hip_runtime.h>

#define RELS 237
#define SPLIT 3            // blocks per relation, each owns an index RANGE (disjoint)
#define DIM 128
#define CH 32              // triples per chunk
#define LISTCAP 512        // >> max triples per (relation, third-range) (~23 mean)
#define EPS 1e-12f

typedef __attribute__((ext_vector_type(8))) short bf16x8;
typedef __attribute__((ext_vector_type(4))) float f32x4;

__device__ __forceinline__ unsigned short f2bf(float f) {
    unsigned int u = __float_as_uint(f);
    u = (u + 0x7fffu + ((u >> 16) & 1u)) >> 16;   // RNE
    return (unsigned short)u;
}

// One kernel, zero cross-block communication, zero workspace use, and
// BIT-DETERMINISTIC (graph-replay tripwire). Block (r, third) owns triples
// with index in [third*n/3, (third+1)*n/3) whose relation == r. SPLIT=3:
// per-block count ~23 so ~97% of blocks run exactly ONE chunk pipeline
// (vs 2 at SPLIT=2), and LDS = 51.9 KB (LISTCAP=512) allows 3 blocks/CU so
// all 711 blocks are co-resident at 12 waves/CU. List built with the
// deterministic two-pass method (count -> wave __shfl_up scan, 1 barrier ->
// ordered write). R staging issued BEFORE the scan so its 64 KB of global
// loads fly under the scan's compute. Then the verified MFMA + epilogue.
__global__ __launch_bounds__(256) void relkern(
    const float* __restrict__ ent,
    const int*   __restrict__ h_ids,
    const int*   __restrict__ r_typ,
    const int*   __restrict__ t_ids,
    float*       __restrict__ out,
    int n)
{
    __shared__ unsigned short Bf[16384];   // 32 KB: R as bf16, fragment-linear
    __shared__ int list[LISTCAP];          // triple indices for this (rel, range)
    __shared__ int wtot[4];                // per-wave match totals
    __shared__ char smem[17152];           // Hb (8.7 KB) / Pp (16.9 KB) union + sidx/tRow
    unsigned short* Hb = (unsigned short*)smem;
    float* Pp  = (float*)smem;
    int*  sidx = (int*)(smem + 16896);
    int*  tRow = (int*)(smem + 17024);

    const int r    = blockIdx.x;           // relation
    const int part = blockIdx.y;           // index-range this block owns
    const int tid  = threadIdx.x;
    const int lane = tid & 63;
    const int w    = tid >> 6;

    // ---- stage R fp32 -> bf16 fragment-linear in LDS (issued first: global
    // loads overlap the scan below; the chunk-loop top barrier covers it)
    // fragment idx = ((nt*4+ks)*4+q)*16 + c  holds R[nt*16+c][ks*32+q*8 .. +8]
    const float* src = ent + ((long)r << 14);
    #pragma unroll
    for (int s = 0; s < 8; ++s) {
        int idx = s * 256 + tid;           // b128 index 0..2047
        int c  = idx & 15;
        int q  = (idx >> 4) & 3;
        int ks = (idx >> 6) & 3;
        int nt = idx >> 8;
        const float* sp = src + (nt * 16 + c) * 128 + ks * 32 + q * 8;
        float4 v0 = *(const float4*)sp;
        float4 v1 = *(const float4*)(sp + 4);
        uint4 wv;
        wv.x = f2bf(v0.x) | ((unsigned)f2bf(v0.y) << 16);
        wv.y = f2bf(v0.z) | ((unsigned)f2bf(v0.w) << 16);
        wv.z = f2bf(v1.x) | ((unsigned)f2bf(v1.y) << 16);
        wv.w = f2bf(v1.z) | ((unsigned)f2bf(v1.w) << 16);
        *(uint4*)(Bf + (long)idx * 8) = wv;
    }

    // ---- deterministic list build over this block's range.
    const int rs = (int)(((long)part * n) / SPLIT);
    const int re = (int)(((long)(part + 1) * n) / SPLIT);
    const int va = (rs + 3) & ~3;          // aligned vector region [va, vb)
    const int vb = re & ~3;

    // Pass 1: per-thread match count (stride-256 slices, int4 loads)
    int mycnt = 0;
    for (int i = rs + tid; i < va && i < re; i += 256)
        mycnt += (r_typ[i] == r);
    for (int i4 = (va >> 2) + tid; i4 < (vb >> 2); i4 += 256) {
        int4 v = ((const int4*)r_typ)[i4];
        mycnt += (v.x == r) + (v.y == r) + (v.z == r) + (v.w == r);
    }
    for (int i = (vb > va ? vb : va) + tid; i < re; i += 256)
        mycnt += (r_typ[i] == r);

    // Wave-level inclusive scan (deterministic: lane order == tid order)
    int inc = mycnt;
    #pragma unroll
    for (int off = 1; off < 64; off <<= 1) {
        int v = __shfl_up(inc, off, 64);
        if (lane >= off) inc += v;
    }
    if (lane == 63) wtot[w] = inc;
    __syncthreads();
    int wbase = 0, cnt = 0;
    #pragma unroll
    for (int ww = 0; ww < 4; ++ww) {
        int t = wtot[ww];
        if (ww < w) wbase += t;
        cnt += t;
    }
    int pos = wbase + inc - mycnt;         // exclusive prefix = my write base
    if (cnt > LISTCAP) cnt = LISTCAP;

    // Pass 2: re-read (L1-hot) and write matches in deterministic order
    for (int i = rs + tid; i < va && i < re; i += 256)
        if (r_typ[i] == r && pos < LISTCAP) list[pos++] = i;
    for (int i4 = (va >> 2) + tid; i4 < (vb >> 2); i4 += 256) {
        int4 v = ((const int4*)r_typ)[i4];
        int i = i4 << 2;
        if (v.x == r && pos < LISTCAP) list[pos++] = i;
        if (v.y == r && pos < LISTCAP) list[pos++] = i + 1;
        if (v.z == r && pos < LISTCAP) list[pos++] = i + 2;
        if (v.w == r && pos < LISTCAP) list[pos++] = i + 3;
    }
    for (int i = (vb > va ? vb : va) + tid; i < re; i += 256)
        if (r_typ[i] == r && pos < LISTCAP) list[pos++] = i;

    const int nch = (cnt + CH - 1) >> 5;
    if (nch == 0) return;                  // block-uniform

    const int q = lane >> 4, c = lane & 15;
    const unsigned short* A0p = Hb + c * 136 + q * 8;
    const unsigned short* A1p = Hb + (c + 16) * 136 + q * 8;
    const unsigned short* Bp  = Bf + w * 4096 + q * 128 + c * 8;  // LDS, contiguous/wave

    for (int j = 0; j < nch; ++j) {
        const int base = j * CH;
        int len = cnt - base; if (len > CH) len = CH;

        // barrier: (iter 0) Bf staging + list writes done; (iter>0) prior
        // epilogue's Pp/tRow reads done
        __syncthreads();
        if (tid < CH) {
            int tc = tid < len ? tid : len - 1;
            int t3 = list[base + tc];
            sidx[tid] = t3;
            tRow[tid] = t_ids[t3];
        }
        // ---- stage h rows (32 x 512B fp32 -> bf16, padded stride 136)
        #pragma unroll
        for (int s = 0; s < 4; ++s) {
            int g = s * 256 + tid;
            int trow = g >> 5, c4 = g & 31;
            int tc = trow < len ? trow : len - 1;
            int hid = h_ids[list[base + tc]];
            float4 v = ((const float4*)ent)[((long)hid << 5) + c4];
            ushort4 bb; bb.x = f2bf(v.x); bb.y = f2bf(v.y); bb.z = f2bf(v.z); bb.w = f2bf(v.w);
            *(ushort4*)(Hb + trow * 136 + c4 * 4) = bb;
        }
        __syncthreads();

        // ---- MFMA: wave w owns output cols [w*32, w*32+32)
        f32x4 a00 = {0.f,0.f,0.f,0.f}, a01 = a00, a10 = a00, a11 = a00;
        #pragma unroll
        for (int ks = 0; ks < 4; ++ks) {
            bf16x8 B0 = *(const bf16x8*)(Bp + ks * 512);
            bf16x8 B1 = *(const bf16x8*)(Bp + 2048 + ks * 512);
            bf16x8 A0 = *(const bf16x8*)(A0p + ks * 32);
            bf16x8 A1 = *(const bf16x8*)(A1p + ks * 32);
            a00 = __builtin_amdgcn_mfma_f32_16x16x32_bf16(A0, B0, a00, 0, 0, 0);
            a01 = __builtin_amdgcn_mfma_f32_16x16x32_bf16(A0, B1, a01, 0, 0, 0);
            a10 = __builtin_amdgcn_mfma_f32_16x16x32_bf16(A1, B0, a10, 0, 0, 0);
            a11 = __builtin_amdgcn_mfma_f32_16x16x32_bf16(A1, B1, a11, 0, 0, 0);
        }
        __syncthreads();   // Hb dead; Pp aliases it

        // ---- write prod to LDS: D layout col=lane&15, row=(lane>>4)*4+reg
        #pragma unroll
        for (int reg = 0; reg < 4; ++reg) {
            int m0 = q * 4 + reg;
            Pp[m0 * 132        + w * 32      + c] = a00[reg];
            Pp[m0 * 132        + w * 32 + 16 + c] = a01[reg];
            Pp[(m0 + 16) * 132 + w * 32      + c] = a10[reg];
            Pp[(m0 + 16) * 132 + w * 32 + 16 + c] = a11[reg];
        }
        __syncthreads();

        // ---- epilogue: prefetch t-rows/prod into regs, then reduce
        float p0v[8], p1v[8], t0v[8], t1v[8];
        #pragma unroll
        for (int tt = 0; tt < 8; ++tt) {
            int t = w * 8 + tt;
            int trow = tRow[t];
            const float* tv = ent + ((long)trow << 7);
            t0v[tt] = tv[lane];
            t1v[tt] = tv[lane + 64];
            p0v[tt] = Pp[t * 132 + lane];
            p1v[tt] = Pp[t * 132 + 64 + lane];
        }
        #pragma unroll
        for (int tt = 0; tt < 8; ++tt) {
            int t   = w * 8 + tt;
            float p0 = p0v[tt], p1 = p1v[tt];
            float tv0 = t0v[tt], tv1 = t1v[tt];
            float sp  = p0 * p0 + p1 * p1;
            float st  = tv0 * tv0 + tv1 * tv1;
            float spt = p0 * tv0 + p1 * tv1;
            #pragma unroll
            for (int m = 32; m >= 1; m >>= 1) {
                sp  += __shfl_xor(sp,  m, 64);
                st  += __shfl_xor(st,  m, 64);
                spt += __shfl_xor(spt, m, 64);
            }
            if (lane == 0 && t < len) {
                float npn = fmaxf(sqrtf(sp), EPS);
                float ntn = fmaxf(sqrtf(st), EPS);
                float v   = 2.0f - 2.0f * (spt / (npn * ntn));
                out[sidx[t]] = sqrtf(fmaxf(v, 0.0f));
            }
        }
    }
}

extern "C" void kernel_launch(void* const* d_in, const int* in_sizes, int n_in,
                              void* d_out, int out_size, void* d_ws, size_t ws_size,
                              hipStream_t stream) {
    const float* ent   = (const float*)d_in[0];
    const int*   h_ids = (const int*)d_in[1];
    const int*   r_typ = (const int*)d_in[2];
    const int*   t_ids = (const int*)d_in[3];
    float* out = (float*)d_out;
    const int n = in_sizes[1];

    hipLaunchKernelGGL(relkern, dim3(RELS, SPLIT), dim3(256), 0, stream,
                       ent, h_ids, r_typ, t_ids, out, n);
}

// Round 7
// 101.111 us; speedup vs baseline: 1.0270x; 1.0270x over previous
//
#include <hip/hip_runtime.h>

#define RELS 237
#define SPLIT 2            // blocks per relation, each owns an index RANGE (disjoint)
#define DIM 128
#define CH 32              // triples per chunk
#define LISTCAP 1024       // >> max triples per (relation, half-range) (~35 mean)
#define EPS 1e-12f

typedef __attribute__((ext_vector_type(8))) short bf16x8;
typedef __attribute__((ext_vector_type(4))) float f32x4;

__device__ __forceinline__ unsigned short f2bf(float f) {
    unsigned int u = __float_as_uint(f);
    u = (u + 0x7fffu + ((u >> 16) & 1u)) >> 16;   // RNE
    return (unsigned short)u;
}

// One kernel, zero cross-block communication, zero workspace use, and
// BIT-DETERMINISTIC (graph-replay tripwire). Block (r, half) owns triples
// with index in [half*n/2, (half+1)*n/2) whose relation == r.
// XCD-PAIRING SWIZZLE: workgroups dispatch round-robin across the 8 XCDs
// (wg i -> XCD i%8), so the block index is arranged as
//   bid = slot*8 + xcd,  slot = 2*(r/8) + half,  r = (slot/2)*8 + xcd
// which places BOTH blocks of a relation pair on the SAME XCD: the second
// block's 64 KB R read hits that XCD's L2 / merges in flight instead of
// refetching from HBM (R-staging duplication was the measured marginal cost
// of SPLIT; SPLIT=3 regressed +1.9us for exactly this reason). Mapping is
// performance-only; correctness never depends on XCD assignment.
// List built with the deterministic two-pass method (count -> wave __shfl_up
// scan, 1 barrier -> ordered write). R staging issued BEFORE the scan so its
// global loads fly under the scan's compute. Then the verified MFMA+epilogue.
__global__ __launch_bounds__(256) void relkern(
    const float* __restrict__ ent,
    const int*   __restrict__ h_ids,
    const int*   __restrict__ r_typ,
    const int*   __restrict__ t_ids,
    float*       __restrict__ out,
    int n)
{
    __shared__ unsigned short Bf[16384];   // 32 KB: R as bf16, fragment-linear
    __shared__ int list[LISTCAP];          // triple indices for this (rel, range)
    __shared__ int wtot[4];                // per-wave match totals
    __shared__ char smem[17152];           // Hb (8.7 KB) / Pp (16.9 KB) union + sidx/tRow
    unsigned short* Hb = (unsigned short*)smem;
    float* Pp  = (float*)smem;
    int*  sidx = (int*)(smem + 16896);
    int*  tRow = (int*)(smem + 17024);

    // ---- XCD-pairing decode (grid = 8 * 2 * ceil(237/8) = 480 blocks)
    const int xcd  = blockIdx.x & 7;
    const int slot = blockIdx.x >> 3;
    const int half = slot & 1;
    const int r    = (slot >> 1) * 8 + xcd;
    if (r >= RELS) return;
    const int tid  = threadIdx.x;
    const int lane = tid & 63;
    const int w    = tid >> 6;

    // ---- stage R fp32 -> bf16 fragment-linear in LDS (issued first: global
    // loads overlap the scan below; the chunk-loop top barrier covers it)
    // fragment idx = ((nt*4+ks)*4+q)*16 + c  holds R[nt*16+c][ks*32+q*8 .. +8]
    const float* src = ent + ((long)r << 14);
    #pragma unroll
    for (int s = 0; s < 8; ++s) {
        int idx = s * 256 + tid;           // b128 index 0..2047
        int c  = idx & 15;
        int q  = (idx >> 4) & 3;
        int ks = (idx >> 6) & 3;
        int nt = idx >> 8;
        const float* sp = src + (nt * 16 + c) * 128 + ks * 32 + q * 8;
        float4 v0 = *(const float4*)sp;
        float4 v1 = *(const float4*)(sp + 4);
        uint4 wv;
        wv.x = f2bf(v0.x) | ((unsigned)f2bf(v0.y) << 16);
        wv.y = f2bf(v0.z) | ((unsigned)f2bf(v0.w) << 16);
        wv.z = f2bf(v1.x) | ((unsigned)f2bf(v1.y) << 16);
        wv.w = f2bf(v1.z) | ((unsigned)f2bf(v1.w) << 16);
        *(uint4*)(Bf + (long)idx * 8) = wv;
    }

    // ---- deterministic list build over this block's half range.
    const int rs = (int)(((long)half * n) / SPLIT);
    const int re = (int)(((long)(half + 1) * n) / SPLIT);
    const int va = (rs + 3) & ~3;          // aligned vector region [va, vb)
    const int vb = re & ~3;

    // Pass 1: per-thread match count (stride-256 slices, int4 loads)
    int mycnt = 0;
    for (int i = rs + tid; i < va && i < re; i += 256)
        mycnt += (r_typ[i] == r);
    for (int i4 = (va >> 2) + tid; i4 < (vb >> 2); i4 += 256) {
        int4 v = ((const int4*)r_typ)[i4];
        mycnt += (v.x == r) + (v.y == r) + (v.z == r) + (v.w == r);
    }
    for (int i = (vb > va ? vb : va) + tid; i < re; i += 256)
        mycnt += (r_typ[i] == r);

    // Wave-level inclusive scan (deterministic: lane order == tid order)
    int inc = mycnt;
    #pragma unroll
    for (int off = 1; off < 64; off <<= 1) {
        int v = __shfl_up(inc, off, 64);
        if (lane >= off) inc += v;
    }
    if (lane == 63) wtot[w] = inc;
    __syncthreads();
    int wbase = 0, cnt = 0;
    #pragma unroll
    for (int ww = 0; ww < 4; ++ww) {
        int t = wtot[ww];
        if (ww < w) wbase += t;
        cnt += t;
    }
    int pos = wbase + inc - mycnt;         // exclusive prefix = my write base
    if (cnt > LISTCAP) cnt = LISTCAP;

    // Pass 2: re-read (L1-hot) and write matches in deterministic order
    for (int i = rs + tid; i < va && i < re; i += 256)
        if (r_typ[i] == r && pos < LISTCAP) list[pos++] = i;
    for (int i4 = (va >> 2) + tid; i4 < (vb >> 2); i4 += 256) {
        int4 v = ((const int4*)r_typ)[i4];
        int i = i4 << 2;
        if (v.x == r && pos < LISTCAP) list[pos++] = i;
        if (v.y == r && pos < LISTCAP) list[pos++] = i + 1;
        if (v.z == r && pos < LISTCAP) list[pos++] = i + 2;
        if (v.w == r && pos < LISTCAP) list[pos++] = i + 3;
    }
    for (int i = (vb > va ? vb : va) + tid; i < re; i += 256)
        if (r_typ[i] == r && pos < LISTCAP) list[pos++] = i;

    const int nch = (cnt + CH - 1) >> 5;
    if (nch == 0) return;                  // block-uniform

    const int q = lane >> 4, c = lane & 15;
    const unsigned short* A0p = Hb + c * 136 + q * 8;
    const unsigned short* A1p = Hb + (c + 16) * 136 + q * 8;
    const unsigned short* Bp  = Bf + w * 4096 + q * 128 + c * 8;  // LDS, contiguous/wave

    for (int j = 0; j < nch; ++j) {
        const int base = j * CH;
        int len = cnt - base; if (len > CH) len = CH;

        // barrier: (iter 0) Bf staging + list writes done; (iter>0) prior
        // epilogue's Pp/tRow reads done
        __syncthreads();
        if (tid < CH) {
            int tc = tid < len ? tid : len - 1;
            int t3 = list[base + tc];
            sidx[tid] = t3;
            tRow[tid] = t_ids[t3];
        }
        // ---- stage h rows (32 x 512B fp32 -> bf16, padded stride 136)
        #pragma unroll
        for (int s = 0; s < 4; ++s) {
            int g = s * 256 + tid;
            int trow = g >> 5, c4 = g & 31;
            int tc = trow < len ? trow : len - 1;
            int hid = h_ids[list[base + tc]];
            float4 v = ((const float4*)ent)[((long)hid << 5) + c4];
            ushort4 bb; bb.x = f2bf(v.x); bb.y = f2bf(v.y); bb.z = f2bf(v.z); bb.w = f2bf(v.w);
            *(ushort4*)(Hb + trow * 136 + c4 * 4) = bb;
        }
        __syncthreads();

        // ---- MFMA: wave w owns output cols [w*32, w*32+32)
        f32x4 a00 = {0.f,0.f,0.f,0.f}, a01 = a00, a10 = a00, a11 = a00;
        #pragma unroll
        for (int ks = 0; ks < 4; ++ks) {
            bf16x8 B0 = *(const bf16x8*)(Bp + ks * 512);
            bf16x8 B1 = *(const bf16x8*)(Bp + 2048 + ks * 512);
            bf16x8 A0 = *(const bf16x8*)(A0p + ks * 32);
            bf16x8 A1 = *(const bf16x8*)(A1p + ks * 32);
            a00 = __builtin_amdgcn_mfma_f32_16x16x32_bf16(A0, B0, a00, 0, 0, 0);
            a01 = __builtin_amdgcn_mfma_f32_16x16x32_bf16(A0, B1, a01, 0, 0, 0);
            a10 = __builtin_amdgcn_mfma_f32_16x16x32_bf16(A1, B0, a10, 0, 0, 0);
            a11 = __builtin_amdgcn_mfma_f32_16x16x32_bf16(A1, B1, a11, 0, 0, 0);
        }
        __syncthreads();   // Hb dead; Pp aliases it

        // ---- write prod to LDS: D layout col=lane&15, row=(lane>>4)*4+reg
        #pragma unroll
        for (int reg = 0; reg < 4; ++reg) {
            int m0 = q * 4 + reg;
            Pp[m0 * 132        + w * 32      + c] = a00[reg];
            Pp[m0 * 132        + w * 32 + 16 + c] = a01[reg];
            Pp[(m0 + 16) * 132 + w * 32      + c] = a10[reg];
            Pp[(m0 + 16) * 132 + w * 32 + 16 + c] = a11[reg];
        }
        __syncthreads();

        // ---- epilogue: prefetch t-rows/prod into regs, then reduce
        float p0v[8], p1v[8], t0v[8], t1v[8];
        #pragma unroll
        for (int tt = 0; tt < 8; ++tt) {
            int t = w * 8 + tt;
            int trow = tRow[t];
            const float* tv = ent + ((long)trow << 7);
            t0v[tt] = tv[lane];
            t1v[tt] = tv[lane + 64];
            p0v[tt] = Pp[t * 132 + lane];
            p1v[tt] = Pp[t * 132 + 64 + lane];
        }
        #pragma unroll
        for (int tt = 0; tt < 8; ++tt) {
            int t   = w * 8 + tt;
            float p0 = p0v[tt], p1 = p1v[tt];
            float tv0 = t0v[tt], tv1 = t1v[tt];
            float sp  = p0 * p0 + p1 * p1;
            float st  = tv0 * tv0 + tv1 * tv1;
            float spt = p0 * tv0 + p1 * tv1;
            #pragma unroll
            for (int m = 32; m >= 1; m >>= 1) {
                sp  += __shfl_xor(sp,  m, 64);
                st  += __shfl_xor(st,  m, 64);
                spt += __shfl_xor(spt, m, 64);
            }
            if (lane == 0 && t < len) {
                float npn = fmaxf(sqrtf(sp), EPS);
                float ntn = fmaxf(sqrtf(st), EPS);
                float v   = 2.0f - 2.0f * (spt / (npn * ntn));
                out[sidx[t]] = sqrtf(fmaxf(v, 0.0f));
            }
        }
    }
}

extern "C" void kernel_launch(void* const* d_in, const int* in_sizes, int n_in,
                              void* d_out, int out_size, void* d_ws, size_t ws_size,
                              hipStream_t stream) {
    const float* ent   = (const float*)d_in[0];
    const int*   h_ids = (const int*)d_in[1];
    const int*   r_typ = (const int*)d_in[2];
    const int*   t_ids = (const int*)d_in[3];
    float* out = (float*)d_out;
    const int n = in_sizes[1];

    // grid: 8 XCD lanes * (2 * ceil(RELS/8)) slots = 480 blocks
    hipLaunchKernelGGL(relkern, dim3(8 * 2 * ((RELS + 7) / 8)), dim3(256), 0, stream,
                       ent, h_ids, r_typ, t_ids, out, n);
}